// Round 6
// baseline (902.006 us; speedup 1.0000x reference)
//
#include <hip/hip_runtime.h>
#include <math.h>

#define HH 128      // hidden
#define DD 2048     // input size
#define BATCH 64
#define TT 256
#define G4 512      // 4*H
#define GB 16       // batches per recurrence block (4 blocks)
#define HPAD 136    // padded h row length (halves)

typedef __attribute__((ext_vector_type(8))) short bf16x8;   // 8 bf16
typedef __attribute__((ext_vector_type(4))) float f32x4;
typedef _Float16 f16x8 __attribute__((ext_vector_type(8))); // 8 fp16

// xp layout (permuted for coalesced recurrence loads):
//   elem(t, b, n')  with blk=b>>4, lb=b&15, w=n'>>6, mm=(n'>>4)&3, low=n'&15
//   addr = t*32768 + blk*8192 + w*1024 + mm*256 + lb*16 + low
// n' = 4u+g (gate-interleaved): original gate row = g*128+u.

// ---- helpers ---------------------------------------------------------------
static __device__ __forceinline__ unsigned short f2bf_rne(float f) {
    union { float f; unsigned u; } v; v.f = f;
    unsigned r = v.u + 0x7fff + ((v.u >> 16) & 1);
    return (unsigned short)(r >> 16);
}
static __device__ __forceinline__ float bf2f(unsigned short b) {
    union { unsigned u; float f; } v; v.u = ((unsigned)b) << 16;
    return v.f;
}
static __device__ __forceinline__ float fexp2(float x) {
#if __has_builtin(__builtin_amdgcn_exp2f)
    return __builtin_amdgcn_exp2f(x);
#else
    return exp2f(x);
#endif
}
static __device__ __forceinline__ float frcp(float x) {
#if __has_builtin(__builtin_amdgcn_rcpf)
    return __builtin_amdgcn_rcpf(x);
#else
    return 1.f / x;
#endif
}
static __device__ __forceinline__ float sigmoid_f(float x) {
    return frcp(1.f + fexp2(-1.44269504f * x));
}
static __device__ __forceinline__ float tanh_f(float x) {
    float xx = fminf(fmaxf(x, -15.f), 15.f);
    float e = fexp2(2.88539008f * xx);               // exp(2x)
    return 1.f - 2.f * frcp(e + 1.f);
}

// ---------------------------------------------------------------------------
// Split-bf16 GEMM (validated R2-R4): xp(t,b,n') permuted output.
// ---------------------------------------------------------------------------
#define PK 40   // LDS row stride in halves (80 B)

__global__ __launch_bounds__(256) void gemm_split_bf16(
    const float* __restrict__ A, const float* __restrict__ Bw,
    const float* __restrict__ b1, const float* __restrict__ b2,
    float* __restrict__ C, int M, int N, int K)
{
    __shared__ unsigned short Ah[128 * PK], Al[128 * PK];
    __shared__ unsigned short Bh[128 * PK], Bl[128 * PK];

    const int tid = threadIdx.x;
    const int l = tid & 63;
    const int w = tid >> 6;
    const int wr = w >> 1, wc = w & 1;
    const int bm = blockIdx.y, bn = blockIdx.x;

    f32x4 acc[4][4];
#pragma unroll
    for (int m = 0; m < 4; ++m)
#pragma unroll
        for (int n = 0; n < 4; ++n) acc[m][n] = f32x4{0.f, 0.f, 0.f, 0.f};

    const float* Ab = A + (size_t)(bm * 128) * K;

    for (int k0 = 0; k0 < K; k0 += 32) {
        __syncthreads();
#pragma unroll
        for (int q = 0; q < 4; ++q) {
            int fid = tid + 256 * q;
            int r = fid >> 3;
            int kk = (fid & 7) << 2;
            int n = bn * 128 + r;
            int orign = ((n & 3) << 7) | (n >> 2);
            float4 av = *(const float4*)(Ab + (size_t)r * K + k0 + kk);
            float4 bv = *(const float4*)(Bw + (size_t)orign * K + k0 + kk);
            float a4[4] = {av.x, av.y, av.z, av.w};
            float b4[4] = {bv.x, bv.y, bv.z, bv.w};
            ushort4 ahv, alv, bhv, blv;
            unsigned short t;
            t = f2bf_rne(a4[0]); ahv.x = t; alv.x = f2bf_rne(a4[0] - bf2f(t));
            t = f2bf_rne(a4[1]); ahv.y = t; alv.y = f2bf_rne(a4[1] - bf2f(t));
            t = f2bf_rne(a4[2]); ahv.z = t; alv.z = f2bf_rne(a4[2] - bf2f(t));
            t = f2bf_rne(a4[3]); ahv.w = t; alv.w = f2bf_rne(a4[3] - bf2f(t));
            t = f2bf_rne(b4[0]); bhv.x = t; blv.x = f2bf_rne(b4[0] - bf2f(t));
            t = f2bf_rne(b4[1]); bhv.y = t; blv.y = f2bf_rne(b4[1] - bf2f(t));
            t = f2bf_rne(b4[2]); bhv.z = t; blv.z = f2bf_rne(b4[2] - bf2f(t));
            t = f2bf_rne(b4[3]); bhv.w = t; blv.w = f2bf_rne(b4[3] - bf2f(t));
            int off = r * PK + kk;
            *(ushort4*)&Ah[off] = ahv;
            *(ushort4*)&Al[off] = alv;
            *(ushort4*)&Bh[off] = bhv;
            *(ushort4*)&Bl[off] = blv;
        }
        __syncthreads();

        bf16x8 aH[4], aL[4], bH[4], bL[4];
#pragma unroll
        for (int m = 0; m < 4; ++m) {
            int row = wr * 64 + m * 16 + (l & 15);
            int off = row * PK + 8 * (l >> 4);
            aH[m] = *(const bf16x8*)&Ah[off];
            aL[m] = *(const bf16x8*)&Al[off];
        }
#pragma unroll
        for (int n = 0; n < 4; ++n) {
            int row = wc * 64 + n * 16 + (l & 15);
            int off = row * PK + 8 * (l >> 4);
            bH[n] = *(const bf16x8*)&Bh[off];
            bL[n] = *(const bf16x8*)&Bl[off];
        }
#pragma unroll
        for (int m = 0; m < 4; ++m)
#pragma unroll
            for (int n = 0; n < 4; ++n) {
                acc[m][n] = __builtin_amdgcn_mfma_f32_16x16x32_bf16(aH[m], bH[n], acc[m][n], 0, 0, 0);
                acc[m][n] = __builtin_amdgcn_mfma_f32_16x16x32_bf16(aH[m], bL[n], acc[m][n], 0, 0, 0);
                acc[m][n] = __builtin_amdgcn_mfma_f32_16x16x32_bf16(aL[m], bH[n], acc[m][n], 0, 0, 0);
            }
    }

#pragma unroll
    for (int n = 0; n < 4; ++n) {
        int cg = bn * 128 + wc * 64 + n * 16 + (l & 15);
        int orig = ((cg & 3) << 7) | (cg >> 2);
        float bias = b1[orig] + b2[orig];
        size_t cbase = (size_t)(cg >> 6) * 1024 + ((cg >> 4) & 3) * 256 + (cg & 15);
#pragma unroll
        for (int m = 0; m < 4; ++m) {
            int r0 = bm * 128 + wr * 64 + m * 16 + ((l >> 4) << 2);
            f32x4 v = acc[m][n];
#pragma unroll
            for (int i = 0; i < 4; ++i) {
                int r = r0 + i;
                int t = r & 255, b = r >> 8;
                C[(size_t)t * 32768 + (size_t)(b >> 4) * 8192 + cbase + (b & 15) * 16] = v[i] + bias;
            }
        }
    }
}

// ---------------------------------------------------------------------------
// bias1p[n'] = bih1[orig]+bhh1[orig], permuted to gate-interleaved order.
// ---------------------------------------------------------------------------
__global__ void prep_bias1(const float* __restrict__ bih1,
                           const float* __restrict__ bhh1,
                           float* __restrict__ bias1p)
{
    int n = threadIdx.x;                 // 512
    int orig = ((n & 3) << 7) | (n >> 2);
    bias1p[n] = bih1[orig] + bhh1[orig];
}

// ---------------------------------------------------------------------------
// FUSED two-layer LSTM recurrence, wavefront-pipelined.
// Phase p computes h0_{p+1} (layer 0) AND h1_p (layer 1) in one barrier cycle:
//   gates0 = xp0[p+1] + Whh0 @ h0_p
//   gates1 = bias1    + Wih1 @ h0_p + Whh1 @ h1_{p-1}
// h0_p's LDS B-fragments are SHARED by the Whh0 and Wih1 MFMAs.
// 4 blocks x 16 batches, 512 threads (8 waves), f16 MFMA 16x16x32.
// Weights: 192 VGPR/thread resident (Whh0, Wih1, Whh1 frags). B-frags are
// streamed one-at-a-time through the MFMAs to keep peak VGPR ~250.
// h double-buffered per layer -> single barrier/phase.
// ---------------------------------------------------------------------------
__global__ __launch_bounds__(512) void lstm_fused(
    const float* __restrict__ xp,      // permuted xp0 layout (see top)
    const float* __restrict__ Whh0,    // [512,128] original layout
    const float* __restrict__ Wih1,    // [512,128]
    const float* __restrict__ Whh1,    // [512,128]
    const float* __restrict__ bias1p,  // [512] permuted (prep_bias1)
    const float* __restrict__ Wfc,     // [128]
    const float* __restrict__ bfc,     // [1]
    float* __restrict__ out)           // [64]
{
    const int tid = threadIdx.x;
    const int l  = tid & 63;
    const int w  = tid >> 6;     // wave 0..7
    const int lb = l & 15;       // batch lane / MFMA col
    const int lg = l >> 4;       // 0..3
    const int blk = blockIdx.x;

    __shared__ ushort h0b[2][GB][HPAD];
    __shared__ ushort h1b[2][GB][HPAD];
    __shared__ float red[8][GB];

    for (int i = tid; i < 2 * GB * HPAD; i += 512) {
        ((ushort*)h0b)[i] = 0;
        ((ushort*)h1b)[i] = 0;
    }

    // ---- resident weight fragments (fp16), gate-interleaved permutation ---
    // row rp = (w*4+mm)*16 + lb  ->  orig = g*128+u ; K-slice = kt*32 + lg*8
    f16x8 wf0[4][4], wi1[4][4], wh1[4][4];     // [mm][kt], 64 VGPR each
#pragma unroll
    for (int mm = 0; mm < 4; ++mm) {
        int rp = (w * 4 + mm) * 16 + lb;
        int orig = ((rp & 3) << 7) | (rp >> 2);
#pragma unroll
        for (int kt = 0; kt < 4; ++kt) {
            const float* p0 = Whh0 + (size_t)orig * HH + kt * 32 + lg * 8;
            const float* p1 = Wih1 + (size_t)orig * HH + kt * 32 + lg * 8;
            const float* p2 = Whh1 + (size_t)orig * HH + kt * 32 + lg * 8;
            float4 a0 = *(const float4*)p0, a1 = *(const float4*)(p0 + 4);
            float4 b0 = *(const float4*)p1, b1v = *(const float4*)(p1 + 4);
            float4 c0v = *(const float4*)p2, c1v = *(const float4*)(p2 + 4);
            f16x8 f;
            f[0]=(_Float16)a0.x; f[1]=(_Float16)a0.y; f[2]=(_Float16)a0.z; f[3]=(_Float16)a0.w;
            f[4]=(_Float16)a1.x; f[5]=(_Float16)a1.y; f[6]=(_Float16)a1.z; f[7]=(_Float16)a1.w;
            wf0[mm][kt] = f;
            f[0]=(_Float16)b0.x; f[1]=(_Float16)b0.y; f[2]=(_Float16)b0.z; f[3]=(_Float16)b0.w;
            f[4]=(_Float16)b1v.x; f[5]=(_Float16)b1v.y; f[6]=(_Float16)b1v.z; f[7]=(_Float16)b1v.w;
            wi1[mm][kt] = f;
            f[0]=(_Float16)c0v.x; f[1]=(_Float16)c0v.y; f[2]=(_Float16)c0v.z; f[3]=(_Float16)c0v.w;
            f[4]=(_Float16)c1v.x; f[5]=(_Float16)c1v.y; f[6]=(_Float16)c1v.z; f[7]=(_Float16)c1v.w;
            wh1[mm][kt] = f;
        }
    }

    const float* xbase = xp + (size_t)blk * 8192 + w * 1024 + lb * 16 + lg * 4;
    const int ubase = w * 16 + lg;     // u(mm) = ubase + mm*4

    f32x4 X[4];
#pragma unroll
    for (int mm = 0; mm < 4; ++mm) X[mm] = *(const f32x4*)(xbase + mm * 256);

    float c0[4] = {0.f,0.f,0.f,0.f}, c1[4] = {0.f,0.f,0.f,0.f}, hv[4];
    __syncthreads();   // LDS zeroing complete

    // ---- prologue: h0_0 = act(xp0[0]) (h_{-1}=0, c_{-1}=0) ----------------
#pragma unroll
    for (int mm = 0; mm < 4; ++mm) {
        float iv = sigmoid_f(X[mm][0]);
        float fv = sigmoid_f(X[mm][1]);
        float gg = tanh_f(X[mm][2]);
        float ov = sigmoid_f(X[mm][3]);
        float c = fmaf(fv, 0.f, iv * gg);
        c0[mm] = c;
        float h = ov * tanh_f(c);
        union { _Float16 f; ushort s; } hc; hc.f = (_Float16)h;
        h0b[0][lb][ubase + mm * 4] = hc.s;
    }
#pragma unroll
    for (int mm = 0; mm < 4; ++mm)
        X[mm] = *(const f32x4*)(xbase + 32768 + mm * 256);     // xp0[1]
    __syncthreads();   // h0_0 visible

    // ---- main loop: 256 phases --------------------------------------------
    for (int p = 0; p < TT; ++p) {
        const int rb = p & 1, wb = rb ^ 1;

        f32x4 a0[4], a1[4];
#pragma unroll
        for (int mm = 0; mm < 4; ++mm) a0[mm] = X[mm];          // xp0[p+1]
#pragma unroll
        for (int mm = 0; mm < 4; ++mm)
            a1[mm] = *(const f32x4*)(bias1p + (w * 4 + mm) * 16 + lg * 4);

        // layer-0 + layer-1a: shared h0_p B-fragments, streamed per kt
#pragma unroll
        for (int kt = 0; kt < 4; ++kt) {
            union { uint4 u; f16x8 h; } cvt;
            cvt.u = *(const uint4*)&h0b[rb][lb][kt * 32 + lg * 8];
            f16x8 bh = cvt.h;
#pragma unroll
            for (int mm = 0; mm < 4; ++mm)
                a0[mm] = __builtin_amdgcn_mfma_f32_16x16x32_f16(wf0[mm][kt], bh, a0[mm], 0, 0, 0);
#pragma unroll
            for (int mm = 0; mm < 4; ++mm)
                a1[mm] = __builtin_amdgcn_mfma_f32_16x16x32_f16(wi1[mm][kt], bh, a1[mm], 0, 0, 0);
        }
        // layer-1b: h1_{p-1}
#pragma unroll
        for (int kt = 0; kt < 4; ++kt) {
            union { uint4 u; f16x8 h; } cvt;
            cvt.u = *(const uint4*)&h1b[rb][lb][kt * 32 + lg * 8];
            f16x8 bh = cvt.h;
#pragma unroll
            for (int mm = 0; mm < 4; ++mm)
                a1[mm] = __builtin_amdgcn_mfma_f32_16x16x32_f16(wh1[mm][kt], bh, a1[mm], 0, 0, 0);
        }

        // reload X for phase p+1 (consumes xp0[p+2]); latency hides under acts
        int tn = (p + 2 < TT) ? p + 2 : TT - 1;
#pragma unroll
        for (int mm = 0; mm < 4; ++mm)
            X[mm] = *(const f32x4*)(xbase + (size_t)tn * 32768 + mm * 256);

        // activations, lane-local c/h updates, LDS writes (double-buffered)
#pragma unroll
        for (int mm = 0; mm < 4; ++mm) {
            float iv = sigmoid_f(a0[mm][0]);
            float fv = sigmoid_f(a0[mm][1]);
            float gg = tanh_f(a0[mm][2]);
            float ov = sigmoid_f(a0[mm][3]);
            float c = fmaf(fv, c0[mm], iv * gg);
            c0[mm] = c;
            float h = ov * tanh_f(c);
            union { _Float16 f; ushort s; } hc; hc.f = (_Float16)h;
            h0b[wb][lb][ubase + mm * 4] = hc.s;
        }
#pragma unroll
        for (int mm = 0; mm < 4; ++mm) {
            float iv = sigmoid_f(a1[mm][0]);
            float fv = sigmoid_f(a1[mm][1]);
            float gg = tanh_f(a1[mm][2]);
            float ov = sigmoid_f(a1[mm][3]);
            float c = fmaf(fv, c1[mm], iv * gg);
            c1[mm] = c;
            float h = ov * tanh_f(c);
            hv[mm] = h;
            union { _Float16 f; ushort s; } hc; hc.f = (_Float16)h;
            h1b[wb][lb][ubase + mm * 4] = hc.s;
        }
        __syncthreads();
    }

    // ---- fused FC head: out[b] = sum_u h1_255[u]*Wfc[u] + bfc -------------
    float pr = 0.f;
#pragma unroll
    for (int mm = 0; mm < 4; ++mm)
        pr = fmaf(hv[mm], Wfc[ubase + mm * 4], pr);
    pr += __shfl_xor(pr, 16, 64);
    pr += __shfl_xor(pr, 32, 64);
    if (l < GB) red[w][l] = pr;
    __syncthreads();
    if (tid < GB) {
        float s = bfc[0];
#pragma unroll
        for (int q = 0; q < 8; ++q) s += red[q][tid];
        out[blk * GB + tid] = s;
    }
}

// ---------------------------------------------------------------------------
extern "C" void kernel_launch(void* const* d_in, const int* in_sizes, int n_in,
                              void* d_out, int out_size, void* d_ws, size_t ws_size,
                              hipStream_t stream)
{
    const float* x    = (const float*)d_in[0];
    const float* Wih0 = (const float*)d_in[1];
    const float* Whh0 = (const float*)d_in[2];
    const float* bih0 = (const float*)d_in[3];
    const float* bhh0 = (const float*)d_in[4];
    const float* Wih1 = (const float*)d_in[5];
    const float* Whh1 = (const float*)d_in[6];
    const float* bih1 = (const float*)d_in[7];
    const float* bhh1 = (const float*)d_in[8];
    const float* Wfc  = (const float*)d_in[9];
    const float* bfc  = (const float*)d_in[10];
    float* out = (float*)d_out;

    const int M = BATCH * TT;                    // 16384
    float* xp      = (float*)d_ws;               // [16384,512] permuted
    float* bias1p  = xp + (size_t)M * G4;        // [512]

    // 1) xp0 = x @ Wih0_perm^T + bih0 + bhh0 -> permuted layout (34.4 GFLOP)
    gemm_split_bf16<<<dim3(G4 / 128, M / 128), 256, 0, stream>>>(
        x, Wih0, bih0, bhh0, xp, M, G4, DD);

    // 2) permuted layer-1 bias
    prep_bias1<<<1, G4, 0, stream>>>(bih1, bhh1, bias1p);

    // 3) fused 2-layer recurrence + FC head
    lstm_fused<<<BATCH / GB, 512, 0, stream>>>(
        xp, Whh0, Wih1, Whh1, bias1p, Wfc, bfc, out);
}